// Round 7
// baseline (434.785 us; speedup 1.0000x reference)
//
#include <hip/hip_runtime.h>
#include <math.h>

namespace {
constexpr int   NG    = 64;
constexpr int   GC    = NG * NG * NG;
constexpr int   BOUND = 3;
constexpr float DXf    = 1.0f / 64.0f;
constexpr float INV_DX = 64.0f;
constexpr float DTf    = 5e-4f;
constexpr double P_VOL_D = (0.5 / 64.0) * (0.5 / 64.0) * (0.5 / 64.0);
constexpr float P_MASS_F = (float)(P_VOL_D * 1000.0);
constexpr float AFFINE_SCALE = (float)(-5e-4 * P_VOL_D * 4.0 * 64.0 * 64.0);
constexpr float D_INV  = 4.0f * 64.0f * 64.0f;   // 16384
constexpr float GRAV_Y = -9.8f;

__device__ __forceinline__ void atom_add_f32(float* p, float v) {
    unsafeAtomicAdd(p, v);   // hw global_atomic_add_f32, fire-and-forget
}

__device__ __forceinline__ void weights_of(float fx0, float fx1, float fx2, float w[3][3]) {
    w[0][0] = 0.5f*(1.5f-fx0)*(1.5f-fx0); w[0][1] = 0.5f*(1.5f-fx1)*(1.5f-fx1); w[0][2] = 0.5f*(1.5f-fx2)*(1.5f-fx2);
    w[1][0] = 0.75f-(fx0-1.0f)*(fx0-1.0f); w[1][1] = 0.75f-(fx1-1.0f)*(fx1-1.0f); w[1][2] = 0.75f-(fx2-1.0f)*(fx2-1.0f);
    w[2][0] = 0.5f*(fx0-0.5f)*(fx0-0.5f); w[2][1] = 0.5f*(fx1-0.5f)*(fx1-0.5f); w[2][2] = 0.5f*(fx2-0.5f)*(fx2-0.5f);
}

// quadratic B-spline weight at signed offset u; 0 outside |u|<1.5.
// Bit-exact equal to the reference per-offset formulas for u = fx - o.
__device__ __forceinline__ float bspline_w(float u) {
    float au = fabsf(u);
    float a  = 1.5f - au;
    float w  = (au < 0.5f) ? (0.75f - u * u) : (0.5f * a * a);
    return (au < 1.5f) ? w : 0.f;
}
}

// ---------------- pass 1: histogram particles into CELLS (262144 bins) -------
__global__ __launch_bounds__(256) void count_kernel(const float* __restrict__ x,
                                                    int* __restrict__ cnt, int n)
{
    int p = blockIdx.x * 256 + threadIdx.x;
    if (p >= n) return;
    float u0 = x[3*p] * INV_DX, u1 = x[3*p+1] * INV_DX, u2 = x[3*p+2] * INV_DX;
    int b0 = (int)floorf(u0 - 0.5f), b1 = (int)floorf(u1 - 0.5f), b2 = (int)floorf(u2 - 0.5f);
    if ((unsigned)b0 >= 64u || (unsigned)b1 >= 64u || (unsigned)b2 >= 64u) return;
    atomicAdd(&cnt[((b0 << 6) + b1) * 64 + b2], 1);
}

// ---------------- pass 2a: per-256-block exclusive scan, block totals to aux --
__global__ __launch_bounds__(256) void scanA(const int* __restrict__ cnt,
                                             int* __restrict__ start,
                                             int* __restrict__ aux)
{
    __shared__ int sh[256];
    int tid = threadIdx.x;
    int i = blockIdx.x * 256 + tid;
    int v = cnt[i];
    sh[tid] = v;
    __syncthreads();
    for (int off = 1; off < 256; off <<= 1) {
        int t = (tid >= off) ? sh[tid - off] : 0;
        __syncthreads();
        sh[tid] += t;
        __syncthreads();
    }
    start[i] = sh[tid] - v;                 // block-local exclusive
    if (tid == 255) aux[blockIdx.x] = sh[255];
}

// ---------------- pass 2b: scan the 1024 block totals (single block) ---------
__global__ __launch_bounds__(256) void scanB(int* __restrict__ aux,
                                             int* __restrict__ start)
{
    __shared__ int partial[256];
    int tid = threadIdx.x;
    int local[4];
    int s = 0;
#pragma unroll
    for (int i = 0; i < 4; ++i) { local[i] = s; s += aux[tid * 4 + i]; }
    partial[tid] = s;
    __syncthreads();
    for (int off = 1; off < 256; off <<= 1) {
        int v = (tid >= off) ? partial[tid - off] : 0;
        __syncthreads();
        partial[tid] += v;
        __syncthreads();
    }
    int base = (tid > 0) ? partial[tid - 1] : 0;
#pragma unroll
    for (int i = 0; i < 4; ++i) aux[tid * 4 + i] = base + local[i];
    if (tid == 255) start[GC] = partial[255];   // grand total sentinel
}

// ---------------- pass 2c: add block offsets, emit start & cursor ------------
__global__ __launch_bounds__(256) void scanC(int* __restrict__ start,
                                             const int* __restrict__ aux,
                                             int* __restrict__ cursor)
{
    int i = blockIdx.x * 256 + threadIdx.x;
    int v = start[i] + aux[blockIdx.x];
    start[i] = v;
    cursor[i] = v;
}

// ---------------- pass 3: reorder — coalesced read, precompute, payload write
// payload record (64B): [af00,af01,af02,af10][af11,af12,af20,af21][af22,mv0,mv1,mv2][u0,u1,u2,-]
// where u = x*INV_DX is the grid-space position (base+fx combined).
__global__ __launch_bounds__(256) void reorder_kernel(const float* __restrict__ x,
                                                      const float* __restrict__ v,
                                                      const float* __restrict__ C,
                                                      const float* __restrict__ st,
                                                      int* __restrict__ cursor,
                                                      float4* __restrict__ payload, int n)
{
    int p = blockIdx.x * 256 + threadIdx.x;
    if (p >= n) return;

    float u0 = x[3*p] * INV_DX, u1 = x[3*p+1] * INV_DX, u2 = x[3*p+2] * INV_DX;
    int b0 = (int)floorf(u0 - 0.5f), b1 = (int)floorf(u1 - 0.5f), b2 = (int)floorf(u2 - 0.5f);
    if ((unsigned)b0 >= 64u || (unsigned)b1 >= 64u || (unsigned)b2 >= 64u) return;

    float aff[9];
#pragma unroll
    for (int i = 0; i < 9; ++i)
        aff[i] = st[9*p + i] * AFFINE_SCALE + P_MASS_F * C[9*p + i];
    float mv0 = P_MASS_F * v[3*p], mv1 = P_MASS_F * v[3*p+1], mv2 = P_MASS_F * v[3*p+2];

    int pos = atomicAdd(&cursor[((b0 << 6) + b1) * 64 + b2], 1);

    float4* dst = payload + 4 * (size_t)pos;
    dst[0] = make_float4(aff[0], aff[1], aff[2], aff[3]);
    dst[1] = make_float4(aff[4], aff[5], aff[6], aff[7]);
    dst[2] = make_float4(aff[8], mv0, mv1, mv2);
    dst[3] = make_float4(u0, u1, u2, 0.f);
}

// ---------------- pass 4: cell-centric P2G gather, 8 threads per cell --------
// Block = 256 threads = 32 cells x 8 segment-threads. Thread q of a cell scans
// payload segment (o0,o1) = (q/3, q%3) (q==7 also takes segment 8): each is a
// CONTIGUOUS run of cell-sorted particles, exact 27-cell support, no atomics,
// no LDS. The 8 partials merge with a 3-step shfl_down butterfly (8-lane
// groups). Serial dependent-load chain per thread is ~2 segments (~11
// particles) instead of 9 — latency is hidden by 8x more waves.
// Grid normalize+gravity+boundary fused at the q==0 store; no grid memset.
__global__ __launch_bounds__(256) void p2g_cell8(const float4* __restrict__ payload,
                                                 const int* __restrict__ start,
                                                 float* __restrict__ grid)
{
    // XCD-interleaved chunk swizzle (bijective, 8192 blocks):
    // each XCD gets chunks of 16 consecutive block-ids (= 8 consecutive
    // (g0,g1) rows -> shared payload rows in its L2), chunks interleaved
    // across the grid for load balance.
    int w   = blockIdx.x;
    int xcd = w & 7, j = w >> 3;
    int cj  = j >> 4, oj = j & 15;
    int r   = cj * 128 + xcd * 16 + oj;      // [0, 8192)

    int row01 = r >> 1;                      // (g0,g1) row id
    int g0 = row01 >> 6, g1 = row01 & 63;
    int tid = threadIdx.x;
    int cl = tid >> 3, q = tid & 7;          // 32 cells x 8 threads
    int g2 = ((r & 1) << 5) + cl;
    float fg0 = (float)g0, fg1 = (float)g1, fg2 = (float)g2;

    float acc0 = 0.f, acc1 = 0.f, acc2 = 0.f, acc3 = 0.f;
    int klo = (g2 >= 2) ? g2 - 2 : 0;

#define P2G_SEG(SS)                                                          \
    {   int o0 = (SS) / 3, o1 = (SS) % 3;                                    \
        int b0 = g0 - o0, b1 = g1 - o1;                                      \
        if ((unsigned)b0 < 64u && (unsigned)b1 < 64u) {                      \
            int rowp = ((b0 << 6) + b1) << 6;                                \
            int s = start[rowp + klo];                                       \
            int e = start[rowp + g2 + 1];                                    \
            for (int idx = s; idx < e; ++idx) {                              \
                const float4* rec = payload + 4 * (size_t)idx;               \
                float4 r0 = rec[0], r1 = rec[1], r2 = rec[2], r3 = rec[3];   \
                float u0 = r3.x - fg0, u1 = r3.y - fg1, u2 = r3.z - fg2;     \
                float wq = bspline_w(u0) * bspline_w(u1) * bspline_w(u2);    \
                float dp0 = -u0 * DXf, dp1 = -u1 * DXf, dp2 = -u2 * DXf;     \
                acc0 += wq * (r2.y + r0.x * dp0 + r0.y * dp1 + r0.z * dp2);  \
                acc1 += wq * (r2.z + r0.w * dp0 + r1.x * dp1 + r1.y * dp2);  \
                acc2 += wq * (r2.w + r1.z * dp0 + r1.w * dp1 + r2.x * dp2);  \
                acc3 += wq * P_MASS_F;                                       \
            }                                                                \
        }                                                                    \
    }

    P2G_SEG(q)
    if (q == 7) P2G_SEG(8)
#undef P2G_SEG

    // butterfly reduction over the 8-lane group (only lane q==0's result used)
    acc0 += __shfl_down(acc0, 1); acc1 += __shfl_down(acc1, 1);
    acc2 += __shfl_down(acc2, 1); acc3 += __shfl_down(acc3, 1);
    acc0 += __shfl_down(acc0, 2); acc1 += __shfl_down(acc1, 2);
    acc2 += __shfl_down(acc2, 2); acc3 += __shfl_down(acc3, 2);
    acc0 += __shfl_down(acc0, 4); acc1 += __shfl_down(acc1, 4);
    acc2 += __shfl_down(acc2, 4); acc3 += __shfl_down(acc3, 4);

    if (q == 0) {
        // fused grid update: normalize, gravity, boundary
        float v0 = 0.f, v1 = 0.f, v2 = 0.f;
        if (acc3 > 0.f) {
            float mm = fmaxf(acc3, 1e-10f);
            v0 = acc0 / mm;
            v1 = acc1 / mm + DTf * GRAV_Y;
            v2 = acc2 / mm;
        }
        if ((g0 < BOUND && v0 < 0.f) || (g0 >= NG - BOUND && v0 > 0.f)) v0 = 0.f;
        if ((g1 < BOUND && v1 < 0.f) || (g1 >= NG - BOUND && v1 > 0.f)) v1 = 0.f;
        if ((g2 < BOUND && v2 < 0.f) || (g2 >= NG - BOUND && v2 > 0.f)) v2 = 0.f;
        ((float4*)grid)[row01 * 64 + g2] = make_float4(v0, v1, v2, acc3);
    }
}

// ---------------- fallback P2G: direct global atomics ----------------
__global__ __launch_bounds__(256) void p2g_naive(const float* __restrict__ x,
                                                 const float* __restrict__ v,
                                                 const float* __restrict__ C,
                                                 const float* __restrict__ st,
                                                 float* __restrict__ grid, int n)
{
    int p = blockIdx.x * 256 + threadIdx.x;
    if (p >= n) return;

    float xp0 = x[3*p], xp1 = x[3*p+1], xp2 = x[3*p+2];
    float u0 = xp0 * INV_DX, u1 = xp1 * INV_DX, u2 = xp2 * INV_DX;
    float b0f = floorf(u0 - 0.5f), b1f = floorf(u1 - 0.5f), b2f = floorf(u2 - 0.5f);
    int base0 = (int)b0f, base1 = (int)b1f, base2 = (int)b2f;
    float fx0 = u0 - b0f, fx1 = u1 - b1f, fx2 = u2 - b2f;

    float w[3][3];
    weights_of(fx0, fx1, fx2, w);

    float aff[3][3];
#pragma unroll
    for (int i = 0; i < 3; ++i)
#pragma unroll
        for (int j = 0; j < 3; ++j)
            aff[i][j] = st[9*p + 3*i + j] * AFFINE_SCALE + P_MASS_F * C[9*p + 3*i + j];

    float mv0 = P_MASS_F * v[3*p], mv1 = P_MASS_F * v[3*p+1], mv2 = P_MASS_F * v[3*p+2];

#pragma unroll
    for (int i = 0; i < 3; ++i) {
        float dp0 = ((float)i - fx0) * DXf;
#pragma unroll
        for (int j = 0; j < 3; ++j) {
            float dp1 = ((float)j - fx1) * DXf;
            float wij = w[i][0] * w[j][1];
            float m0 = mv0 + aff[0][0]*dp0 + aff[0][1]*dp1;
            float m1 = mv1 + aff[1][0]*dp0 + aff[1][1]*dp1;
            float m2 = mv2 + aff[2][0]*dp0 + aff[2][1]*dp1;
            int cellij = ((base0 + i) * NG + (base1 + j)) * NG + base2;
#pragma unroll
            for (int k = 0; k < 3; ++k) {
                float dp2 = ((float)k - fx2) * DXf;
                float wi = wij * w[k][2];
                float* cptr = grid + 4 * (cellij + k);
                atom_add_f32(cptr + 0, wi * (m0 + aff[0][2]*dp2));
                atom_add_f32(cptr + 1, wi * (m1 + aff[1][2]*dp2));
                atom_add_f32(cptr + 2, wi * (m2 + aff[2][2]*dp2));
                atom_add_f32(cptr + 3, wi * P_MASS_F);
            }
        }
    }
}

// ---------------- grid: normalize, gravity, boundary (fallback path only) ----
__global__ __launch_bounds__(256) void grid_kernel(float* __restrict__ grid)
{
    int g = blockIdx.x * 256 + threadIdx.x;
    if (g >= GC) return;
    float4 val = ((const float4*)grid)[g];
    float m = val.w;
    float v0 = 0.f, v1 = 0.f, v2 = 0.f;
    if (m > 0.f) {
        float mm = fmaxf(m, 1e-10f);
        v0 = val.x / mm;
        v1 = val.y / mm + DTf * GRAV_Y;
        v2 = val.z / mm;
    }
    int ci = g >> 12, cj = (g >> 6) & 63, ck = g & 63;
    if ((ci < BOUND && v0 < 0.f) || (ci >= NG - BOUND && v0 > 0.f)) v0 = 0.f;
    if ((cj < BOUND && v1 < 0.f) || (cj >= NG - BOUND && v1 > 0.f)) v1 = 0.f;
    if ((ck < BOUND && v2 < 0.f) || (ck >= NG - BOUND && v2 > 0.f)) v2 = 0.f;
    ((float4*)grid)[g] = make_float4(v0, v1, v2, m);
}

// ---------------- G2P: gather, advect, update C/F ----------------
__global__ __launch_bounds__(256) void g2p_kernel(const float* __restrict__ x,
                                                  const float* __restrict__ F,
                                                  const float* __restrict__ grid,
                                                  float* __restrict__ out_x,
                                                  float* __restrict__ out_v,
                                                  float* __restrict__ out_C,
                                                  float* __restrict__ out_F,
                                                  int n)
{
    int p = blockIdx.x * 256 + threadIdx.x;
    if (p >= n) return;

    float xp0 = x[3*p], xp1 = x[3*p+1], xp2 = x[3*p+2];
    float t0 = xp0 * INV_DX, t1 = xp1 * INV_DX, t2 = xp2 * INV_DX;
    float b0 = floorf(t0 - 0.5f), b1 = floorf(t1 - 0.5f), b2 = floorf(t2 - 0.5f);
    int   base0 = (int)b0, base1 = (int)b1, base2 = (int)b2;
    float fx0 = t0 - b0, fx1 = t1 - b1, fx2 = t2 - b2;

    float w[3][3];
    weights_of(fx0, fx1, fx2, w);

    float vn0 = 0.f, vn1 = 0.f, vn2 = 0.f;
    float Cn[3][3] = {};

#pragma unroll
    for (int i = 0; i < 3; ++i) {
        float dp0 = ((float)i - fx0) * DXf;
#pragma unroll
        for (int j = 0; j < 3; ++j) {
            float dp1 = ((float)j - fx1) * DXf;
            float wij = w[i][0] * w[j][1];
            int cellij = ((base0 + i) * NG + (base1 + j)) * NG + base2;
#pragma unroll
            for (int k = 0; k < 3; ++k) {
                float dp2 = ((float)k - fx2) * DXf;
                float wi = wij * w[k][2];
                float4 gv = ((const float4*)grid)[cellij + k];
                vn0 += wi * gv.x; vn1 += wi * gv.y; vn2 += wi * gv.z;
                float wx = wi * gv.x, wy = wi * gv.y, wz = wi * gv.z;
                Cn[0][0] += wx * dp0; Cn[0][1] += wx * dp1; Cn[0][2] += wx * dp2;
                Cn[1][0] += wy * dp0; Cn[1][1] += wy * dp1; Cn[1][2] += wy * dp2;
                Cn[2][0] += wz * dp0; Cn[2][1] += wz * dp1; Cn[2][2] += wz * dp2;
            }
        }
    }

#pragma unroll
    for (int i = 0; i < 3; ++i)
#pragma unroll
        for (int j = 0; j < 3; ++j)
            Cn[i][j] *= D_INV;

    out_x[3*p]   = xp0 + DTf * vn0;
    out_x[3*p+1] = xp1 + DTf * vn1;
    out_x[3*p+2] = xp2 + DTf * vn2;
    out_v[3*p]   = vn0; out_v[3*p+1] = vn1; out_v[3*p+2] = vn2;

    float Fp[3][3];
#pragma unroll
    for (int i = 0; i < 3; ++i)
#pragma unroll
        for (int j = 0; j < 3; ++j)
            Fp[i][j] = F[9*p + 3*i + j];

#pragma unroll
    for (int i = 0; i < 3; ++i) {
#pragma unroll
        for (int k = 0; k < 3; ++k) {
            float acc = Cn[i][0]*Fp[0][k] + Cn[i][1]*Fp[1][k] + Cn[i][2]*Fp[2][k];
            out_F[9*p + 3*i + k] = Fp[i][k] + DTf * acc;
            out_C[9*p + 3*i + k] = Cn[i][k];
        }
    }
}

extern "C" void kernel_launch(void* const* d_in, const int* in_sizes, int n_in,
                              void* d_out, int out_size, void* d_ws, size_t ws_size,
                              hipStream_t stream)
{
    const float* x  = (const float*)d_in[0];
    const float* v  = (const float*)d_in[1];
    const float* C  = (const float*)d_in[2];
    const float* F  = (const float*)d_in[3];
    const float* st = (const float*)d_in[4];
    int n = in_sizes[0] / 3;            // in_sizes are ELEMENT counts (floats)

    const size_t grid_bytes = (size_t)GC * 4 * sizeof(float);          // 4 MiB
    // tables live in the dead out-tail [22n, 22n+tab_ints):
    // cnt(GC) + start(GC+1) + cursor(GC) + aux(1024) = 787,457 ints
    const size_t tab_ints   = 3 * (size_t)GC + 1 + 1024;
    // out_size is an ELEMENT count (same units as in_sizes): out = 24n floats,
    // need payload[6n..22n) + tables -> 22n + tab_ints <= out_size.
    const bool   use_tiled  = ws_size >= grid_bytes &&
                              (size_t)out_size >= 22 * (size_t)n + tab_ints;

    float* grid = (float*)d_ws;

    float* out  = (float*)d_out;
    float* out_x = out;
    float* out_v = out + 3 * (size_t)n;
    float* out_C = out + 6 * (size_t)n;
    float* out_F = out + 15 * (size_t)n;
    // payload (16 floats/particle) lives in out[6n .. 22n) — dead until g2p overwrites
    float4* payload = (float4*)(out + 6 * (size_t)n);
    int* tab    = (int*)(out + 22 * (size_t)n);
    int* cnt    = tab;                       // GC
    int* tstart = tab + GC;                  // GC + 1
    int* cursor = tab + 2 * GC + 1;          // GC
    int* aux    = tab + 3 * GC + 1;          // 1024

    int pblocks = (n + 255) / 256;

    if (use_tiled) {
        hipMemsetAsync(cnt, 0, (size_t)GC * sizeof(int), stream);
        count_kernel<<<pblocks, 256, 0, stream>>>(x, cnt, n);
        scanA<<<GC / 256, 256, 0, stream>>>(cnt, tstart, aux);
        scanB<<<1, 256, 0, stream>>>(aux, tstart);
        scanC<<<GC / 256, 256, 0, stream>>>(tstart, aux, cursor);
        reorder_kernel<<<pblocks, 256, 0, stream>>>(x, v, C, st, cursor, payload, n);
        p2g_cell8<<<GC / 32, 256, 0, stream>>>(payload, tstart, grid);
        // grid normalize/gravity/boundary fused into p2g_cell8
    } else {
        hipMemsetAsync(grid, 0, grid_bytes, stream);
        p2g_naive<<<pblocks, 256, 0, stream>>>(x, v, C, st, grid, n);
        grid_kernel<<<GC / 256, 256, 0, stream>>>(grid);
    }

    g2p_kernel<<<pblocks, 256, 0, stream>>>(x, F, grid, out_x, out_v, out_C, out_F, n);
}

// Round 8
// 390.738 us; speedup vs baseline: 1.1127x; 1.1127x over previous
//
#include <hip/hip_runtime.h>
#include <math.h>

namespace {
constexpr int   NG    = 64;
constexpr int   GC    = NG * NG * NG;
constexpr int   BOUND = 3;
constexpr float DXf    = 1.0f / 64.0f;
constexpr float INV_DX = 64.0f;
constexpr float DTf    = 5e-4f;
constexpr double P_VOL_D = (0.5 / 64.0) * (0.5 / 64.0) * (0.5 / 64.0);
constexpr float P_MASS_F = (float)(P_VOL_D * 1000.0);
constexpr float AFFINE_SCALE = (float)(-5e-4 * P_VOL_D * 4.0 * 64.0 * 64.0);
constexpr float D_INV  = 4.0f * 64.0f * 64.0f;   // 16384
constexpr float GRAV_Y = -9.8f;

__device__ __forceinline__ void atom_add_f32(float* p, float v) {
    unsafeAtomicAdd(p, v);   // hw global_atomic_add_f32, fire-and-forget
}

__device__ __forceinline__ void weights_of(float fx0, float fx1, float fx2, float w[3][3]) {
    w[0][0] = 0.5f*(1.5f-fx0)*(1.5f-fx0); w[0][1] = 0.5f*(1.5f-fx1)*(1.5f-fx1); w[0][2] = 0.5f*(1.5f-fx2)*(1.5f-fx2);
    w[1][0] = 0.75f-(fx0-1.0f)*(fx0-1.0f); w[1][1] = 0.75f-(fx1-1.0f)*(fx1-1.0f); w[1][2] = 0.75f-(fx2-1.0f)*(fx2-1.0f);
    w[2][0] = 0.5f*(fx0-0.5f)*(fx0-0.5f); w[2][1] = 0.5f*(fx1-0.5f)*(fx1-0.5f); w[2][2] = 0.5f*(fx2-0.5f)*(fx2-0.5f);
}

// quadratic B-spline weight at signed offset u; 0 outside |u|<1.5.
// Bit-exact equal to the reference per-offset formulas for u = fx - o.
__device__ __forceinline__ float bspline_w(float u) {
    float au = fabsf(u);
    float a  = 1.5f - au;
    float w  = (au < 0.5f) ? (0.75f - u * u) : (0.5f * a * a);
    return (au < 1.5f) ? w : 0.f;
}
}

// ---------------- pass 1: histogram particles into CELLS (262144 bins) -------
__global__ __launch_bounds__(256) void count_kernel(const float* __restrict__ x,
                                                    int* __restrict__ cnt, int n)
{
    int p = blockIdx.x * 256 + threadIdx.x;
    if (p >= n) return;
    float u0 = x[3*p] * INV_DX, u1 = x[3*p+1] * INV_DX, u2 = x[3*p+2] * INV_DX;
    int b0 = (int)floorf(u0 - 0.5f), b1 = (int)floorf(u1 - 0.5f), b2 = (int)floorf(u2 - 0.5f);
    if ((unsigned)b0 >= 64u || (unsigned)b1 >= 64u || (unsigned)b2 >= 64u) return;
    atomicAdd(&cnt[((b0 << 6) + b1) * 64 + b2], 1);
}

// ---------------- pass 2a: per-256-block exclusive scan, block totals to aux --
__global__ __launch_bounds__(256) void scanA(const int* __restrict__ cnt,
                                             int* __restrict__ start,
                                             int* __restrict__ aux)
{
    __shared__ int sh[256];
    int tid = threadIdx.x;
    int i = blockIdx.x * 256 + tid;
    int v = cnt[i];
    sh[tid] = v;
    __syncthreads();
    for (int off = 1; off < 256; off <<= 1) {
        int t = (tid >= off) ? sh[tid - off] : 0;
        __syncthreads();
        sh[tid] += t;
        __syncthreads();
    }
    start[i] = sh[tid] - v;                 // block-local exclusive
    if (tid == 255) aux[blockIdx.x] = sh[255];
}

// ---------------- pass 2b: scan the 1024 block totals (single block) ---------
__global__ __launch_bounds__(256) void scanB(int* __restrict__ aux,
                                             int* __restrict__ start)
{
    __shared__ int partial[256];
    int tid = threadIdx.x;
    int local[4];
    int s = 0;
#pragma unroll
    for (int i = 0; i < 4; ++i) { local[i] = s; s += aux[tid * 4 + i]; }
    partial[tid] = s;
    __syncthreads();
    for (int off = 1; off < 256; off <<= 1) {
        int v = (tid >= off) ? partial[tid - off] : 0;
        __syncthreads();
        partial[tid] += v;
        __syncthreads();
    }
    int base = (tid > 0) ? partial[tid - 1] : 0;
#pragma unroll
    for (int i = 0; i < 4; ++i) aux[tid * 4 + i] = base + local[i];
    if (tid == 255) start[GC] = partial[255];   // grand total sentinel
}

// ---------------- pass 2c: add block offsets, emit start & cursor ------------
__global__ __launch_bounds__(256) void scanC(int* __restrict__ start,
                                             const int* __restrict__ aux,
                                             int* __restrict__ cursor)
{
    int i = blockIdx.x * 256 + threadIdx.x;
    int v = start[i] + aux[blockIdx.x];
    start[i] = v;
    cursor[i] = v;
}

// ---------------- pass 3: reorder — coalesced read, precompute, payload write
// payload record (64B): [af00,af01,af02,af10][af11,af12,af20,af21][af22,mv0,mv1,mv2][u0,u1,u2,-]
// where u = x*INV_DX is the grid-space position (base+fx combined).
__global__ __launch_bounds__(256) void reorder_kernel(const float* __restrict__ x,
                                                      const float* __restrict__ v,
                                                      const float* __restrict__ C,
                                                      const float* __restrict__ st,
                                                      int* __restrict__ cursor,
                                                      float4* __restrict__ payload, int n)
{
    int p = blockIdx.x * 256 + threadIdx.x;
    if (p >= n) return;

    float u0 = x[3*p] * INV_DX, u1 = x[3*p+1] * INV_DX, u2 = x[3*p+2] * INV_DX;
    int b0 = (int)floorf(u0 - 0.5f), b1 = (int)floorf(u1 - 0.5f), b2 = (int)floorf(u2 - 0.5f);
    if ((unsigned)b0 >= 64u || (unsigned)b1 >= 64u || (unsigned)b2 >= 64u) return;

    float aff[9];
#pragma unroll
    for (int i = 0; i < 9; ++i)
        aff[i] = st[9*p + i] * AFFINE_SCALE + P_MASS_F * C[9*p + i];
    float mv0 = P_MASS_F * v[3*p], mv1 = P_MASS_F * v[3*p+1], mv2 = P_MASS_F * v[3*p+2];

    int pos = atomicAdd(&cursor[((b0 << 6) + b1) * 64 + b2], 1);

    float4* dst = payload + 4 * (size_t)pos;
    dst[0] = make_float4(aff[0], aff[1], aff[2], aff[3]);
    dst[1] = make_float4(aff[4], aff[5], aff[6], aff[7]);
    dst[2] = make_float4(aff[8], mv0, mv1, mv2);
    dst[3] = make_float4(u0, u1, u2, 0.f);
}

// ---------------- pass 4: cell-centric P2G gather, 8 threads per cell --------
// Block = 256 threads = 32 cells x 8 segment-threads. Thread q of a cell scans
// payload segment (o0,o1) = (q/3, q%3); segment 8 is processed COOPERATIVELY
// by all 8 threads at stride 8 (balances the old q==7 straggler). Segments are
// contiguous runs of cell-sorted particles: exact 27-cell support, no atomics,
// no LDS. Inner loop is REGISTER-PIPELINED: record idx+stride is staged into a
// second float4 quad while record idx is computed (two 4-load sets in flight;
// VGPR must come back >=40 — at 20 the loads serialize at ~200cy L2 latency
// each, which was round-7's 900cy/iter stall).
// The 8 partials merge with a 3-step shfl_down butterfly; grid normalize +
// gravity + boundary fused at the q==0 store; no grid memset.
__global__ __launch_bounds__(256) void p2g_cell8(const float4* __restrict__ payload,
                                                 const int* __restrict__ start,
                                                 float* __restrict__ grid)
{
    // XCD-interleaved chunk swizzle (bijective, 8192 blocks): each XCD gets
    // chunks of 16 consecutive block-ids (= 8 consecutive (g0,g1) rows ->
    // shared payload rows in its L2), chunks interleaved for load balance.
    int w   = blockIdx.x;
    int xcd = w & 7, j = w >> 3;
    int cj  = j >> 4, oj = j & 15;
    int r   = cj * 128 + xcd * 16 + oj;      // [0, 8192)

    int row01 = r >> 1;                      // (g0,g1) row id
    int g0 = row01 >> 6, g1 = row01 & 63;
    int tid = threadIdx.x;
    int cl = tid >> 3, q = tid & 7;          // 32 cells x 8 threads
    int g2 = ((r & 1) << 5) + cl;
    float fg0 = (float)g0, fg1 = (float)g1, fg2 = (float)g2;

    float acc0 = 0.f, acc1 = 0.f, acc2 = 0.f, acc3 = 0.f;
    int klo = (g2 >= 2) ? g2 - 2 : 0;

#define P2G_SEG(SS, QOFF, STRIDE)                                            \
    {   int o0 = (SS) / 3, o1 = (SS) % 3;                                    \
        int b0 = g0 - o0, b1 = g1 - o1;                                      \
        if ((unsigned)b0 < 64u && (unsigned)b1 < 64u) {                      \
            int rowp = ((b0 << 6) + b1) << 6;                                \
            int s = start[rowp + klo] + (QOFF);                              \
            int e = start[rowp + g2 + 1];                                    \
            float4 c0, c1, c2, c3;                                           \
            if (s < e) {                                                     \
                const float4* rp = payload + 4 * (size_t)s;                  \
                c0 = rp[0]; c1 = rp[1]; c2 = rp[2]; c3 = rp[3];              \
            }                                                                \
            for (int idx = s; idx < e; ) {                                   \
                float4 r0 = c0, r1 = c1, r2 = c2, r3 = c3;                   \
                idx += (STRIDE);                                             \
                if (idx < e) {                                               \
                    const float4* rp = payload + 4 * (size_t)idx;            \
                    c0 = rp[0]; c1 = rp[1]; c2 = rp[2]; c3 = rp[3];          \
                }                                                            \
                float u0 = r3.x - fg0, u1 = r3.y - fg1, u2 = r3.z - fg2;     \
                float wq = bspline_w(u0) * bspline_w(u1) * bspline_w(u2);    \
                float dp0 = -u0 * DXf, dp1 = -u1 * DXf, dp2 = -u2 * DXf;     \
                acc0 += wq * (r2.y + r0.x * dp0 + r0.y * dp1 + r0.z * dp2);  \
                acc1 += wq * (r2.z + r0.w * dp0 + r1.x * dp1 + r1.y * dp2);  \
                acc2 += wq * (r2.w + r1.z * dp0 + r1.w * dp1 + r2.x * dp2);  \
                acc3 += wq * P_MASS_F;                                       \
            }                                                                \
        }                                                                    \
    }

    P2G_SEG(q, 0, 1)          // own segment, dense scan
    P2G_SEG(8, q, 8)          // segment 8 shared by all 8 lanes, stride 8
#undef P2G_SEG

    // butterfly reduction over the 8-lane group (only lane q==0's result used)
    acc0 += __shfl_down(acc0, 1); acc1 += __shfl_down(acc1, 1);
    acc2 += __shfl_down(acc2, 1); acc3 += __shfl_down(acc3, 1);
    acc0 += __shfl_down(acc0, 2); acc1 += __shfl_down(acc1, 2);
    acc2 += __shfl_down(acc2, 2); acc3 += __shfl_down(acc3, 2);
    acc0 += __shfl_down(acc0, 4); acc1 += __shfl_down(acc1, 4);
    acc2 += __shfl_down(acc2, 4); acc3 += __shfl_down(acc3, 4);

    if (q == 0) {
        // fused grid update: normalize, gravity, boundary
        float v0 = 0.f, v1 = 0.f, v2 = 0.f;
        if (acc3 > 0.f) {
            float mm = fmaxf(acc3, 1e-10f);
            v0 = acc0 / mm;
            v1 = acc1 / mm + DTf * GRAV_Y;
            v2 = acc2 / mm;
        }
        if ((g0 < BOUND && v0 < 0.f) || (g0 >= NG - BOUND && v0 > 0.f)) v0 = 0.f;
        if ((g1 < BOUND && v1 < 0.f) || (g1 >= NG - BOUND && v1 > 0.f)) v1 = 0.f;
        if ((g2 < BOUND && v2 < 0.f) || (g2 >= NG - BOUND && v2 > 0.f)) v2 = 0.f;
        ((float4*)grid)[row01 * 64 + g2] = make_float4(v0, v1, v2, acc3);
    }
}

// ---------------- fallback P2G: direct global atomics ----------------
__global__ __launch_bounds__(256) void p2g_naive(const float* __restrict__ x,
                                                 const float* __restrict__ v,
                                                 const float* __restrict__ C,
                                                 const float* __restrict__ st,
                                                 float* __restrict__ grid, int n)
{
    int p = blockIdx.x * 256 + threadIdx.x;
    if (p >= n) return;

    float xp0 = x[3*p], xp1 = x[3*p+1], xp2 = x[3*p+2];
    float u0 = xp0 * INV_DX, u1 = xp1 * INV_DX, u2 = xp2 * INV_DX;
    float b0f = floorf(u0 - 0.5f), b1f = floorf(u1 - 0.5f), b2f = floorf(u2 - 0.5f);
    int base0 = (int)b0f, base1 = (int)b1f, base2 = (int)b2f;
    float fx0 = u0 - b0f, fx1 = u1 - b1f, fx2 = u2 - b2f;

    float w[3][3];
    weights_of(fx0, fx1, fx2, w);

    float aff[3][3];
#pragma unroll
    for (int i = 0; i < 3; ++i)
#pragma unroll
        for (int j = 0; j < 3; ++j)
            aff[i][j] = st[9*p + 3*i + j] * AFFINE_SCALE + P_MASS_F * C[9*p + 3*i + j];

    float mv0 = P_MASS_F * v[3*p], mv1 = P_MASS_F * v[3*p+1], mv2 = P_MASS_F * v[3*p+2];

#pragma unroll
    for (int i = 0; i < 3; ++i) {
        float dp0 = ((float)i - fx0) * DXf;
#pragma unroll
        for (int j = 0; j < 3; ++j) {
            float dp1 = ((float)j - fx1) * DXf;
            float wij = w[i][0] * w[j][1];
            float m0 = mv0 + aff[0][0]*dp0 + aff[0][1]*dp1;
            float m1 = mv1 + aff[1][0]*dp0 + aff[1][1]*dp1;
            float m2 = mv2 + aff[2][0]*dp0 + aff[2][1]*dp1;
            int cellij = ((base0 + i) * NG + (base1 + j)) * NG + base2;
#pragma unroll
            for (int k = 0; k < 3; ++k) {
                float dp2 = ((float)k - fx2) * DXf;
                float wi = wij * w[k][2];
                float* cptr = grid + 4 * (cellij + k);
                atom_add_f32(cptr + 0, wi * (m0 + aff[0][2]*dp2));
                atom_add_f32(cptr + 1, wi * (m1 + aff[1][2]*dp2));
                atom_add_f32(cptr + 2, wi * (m2 + aff[2][2]*dp2));
                atom_add_f32(cptr + 3, wi * P_MASS_F);
            }
        }
    }
}

// ---------------- grid: normalize, gravity, boundary (fallback path only) ----
__global__ __launch_bounds__(256) void grid_kernel(float* __restrict__ grid)
{
    int g = blockIdx.x * 256 + threadIdx.x;
    if (g >= GC) return;
    float4 val = ((const float4*)grid)[g];
    float m = val.w;
    float v0 = 0.f, v1 = 0.f, v2 = 0.f;
    if (m > 0.f) {
        float mm = fmaxf(m, 1e-10f);
        v0 = val.x / mm;
        v1 = val.y / mm + DTf * GRAV_Y;
        v2 = val.z / mm;
    }
    int ci = g >> 12, cj = (g >> 6) & 63, ck = g & 63;
    if ((ci < BOUND && v0 < 0.f) || (ci >= NG - BOUND && v0 > 0.f)) v0 = 0.f;
    if ((cj < BOUND && v1 < 0.f) || (cj >= NG - BOUND && v1 > 0.f)) v1 = 0.f;
    if ((ck < BOUND && v2 < 0.f) || (ck >= NG - BOUND && v2 > 0.f)) v2 = 0.f;
    ((float4*)grid)[g] = make_float4(v0, v1, v2, m);
}

// ---------------- G2P: gather, advect, update C/F ----------------
__global__ __launch_bounds__(256) void g2p_kernel(const float* __restrict__ x,
                                                  const float* __restrict__ F,
                                                  const float* __restrict__ grid,
                                                  float* __restrict__ out_x,
                                                  float* __restrict__ out_v,
                                                  float* __restrict__ out_C,
                                                  float* __restrict__ out_F,
                                                  int n)
{
    int p = blockIdx.x * 256 + threadIdx.x;
    if (p >= n) return;

    float xp0 = x[3*p], xp1 = x[3*p+1], xp2 = x[3*p+2];
    float t0 = xp0 * INV_DX, t1 = xp1 * INV_DX, t2 = xp2 * INV_DX;
    float b0 = floorf(t0 - 0.5f), b1 = floorf(t1 - 0.5f), b2 = floorf(t2 - 0.5f);
    int   base0 = (int)b0, base1 = (int)b1, base2 = (int)b2;
    float fx0 = t0 - b0, fx1 = t1 - b1, fx2 = t2 - b2;

    float w[3][3];
    weights_of(fx0, fx1, fx2, w);

    float vn0 = 0.f, vn1 = 0.f, vn2 = 0.f;
    float Cn[3][3] = {};

#pragma unroll
    for (int i = 0; i < 3; ++i) {
        float dp0 = ((float)i - fx0) * DXf;
#pragma unroll
        for (int j = 0; j < 3; ++j) {
            float dp1 = ((float)j - fx1) * DXf;
            float wij = w[i][0] * w[j][1];
            int cellij = ((base0 + i) * NG + (base1 + j)) * NG + base2;
#pragma unroll
            for (int k = 0; k < 3; ++k) {
                float dp2 = ((float)k - fx2) * DXf;
                float wi = wij * w[k][2];
                float4 gv = ((const float4*)grid)[cellij + k];
                vn0 += wi * gv.x; vn1 += wi * gv.y; vn2 += wi * gv.z;
                float wx = wi * gv.x, wy = wi * gv.y, wz = wi * gv.z;
                Cn[0][0] += wx * dp0; Cn[0][1] += wx * dp1; Cn[0][2] += wx * dp2;
                Cn[1][0] += wy * dp0; Cn[1][1] += wy * dp1; Cn[1][2] += wy * dp2;
                Cn[2][0] += wz * dp0; Cn[2][1] += wz * dp1; Cn[2][2] += wz * dp2;
            }
        }
    }

#pragma unroll
    for (int i = 0; i < 3; ++i)
#pragma unroll
        for (int j = 0; j < 3; ++j)
            Cn[i][j] *= D_INV;

    out_x[3*p]   = xp0 + DTf * vn0;
    out_x[3*p+1] = xp1 + DTf * vn1;
    out_x[3*p+2] = xp2 + DTf * vn2;
    out_v[3*p]   = vn0; out_v[3*p+1] = vn1; out_v[3*p+2] = vn2;

    float Fp[3][3];
#pragma unroll
    for (int i = 0; i < 3; ++i)
#pragma unroll
        for (int j = 0; j < 3; ++j)
            Fp[i][j] = F[9*p + 3*i + j];

#pragma unroll
    for (int i = 0; i < 3; ++i) {
#pragma unroll
        for (int k = 0; k < 3; ++k) {
            float acc = Cn[i][0]*Fp[0][k] + Cn[i][1]*Fp[1][k] + Cn[i][2]*Fp[2][k];
            out_F[9*p + 3*i + k] = Fp[i][k] + DTf * acc;
            out_C[9*p + 3*i + k] = Cn[i][k];
        }
    }
}

extern "C" void kernel_launch(void* const* d_in, const int* in_sizes, int n_in,
                              void* d_out, int out_size, void* d_ws, size_t ws_size,
                              hipStream_t stream)
{
    const float* x  = (const float*)d_in[0];
    const float* v  = (const float*)d_in[1];
    const float* C  = (const float*)d_in[2];
    const float* F  = (const float*)d_in[3];
    const float* st = (const float*)d_in[4];
    int n = in_sizes[0] / 3;            // in_sizes are ELEMENT counts (floats)

    const size_t grid_bytes = (size_t)GC * 4 * sizeof(float);          // 4 MiB
    // tables live in the dead out-tail [22n, 22n+tab_ints):
    // cnt(GC) + start(GC+1) + cursor(GC) + aux(1024) = 787,457 ints
    const size_t tab_ints   = 3 * (size_t)GC + 1 + 1024;
    // out_size is an ELEMENT count (same units as in_sizes): out = 24n floats,
    // need payload[6n..22n) + tables -> 22n + tab_ints <= out_size.
    const bool   use_tiled  = ws_size >= grid_bytes &&
                              (size_t)out_size >= 22 * (size_t)n + tab_ints;

    float* grid = (float*)d_ws;

    float* out  = (float*)d_out;
    float* out_x = out;
    float* out_v = out + 3 * (size_t)n;
    float* out_C = out + 6 * (size_t)n;
    float* out_F = out + 15 * (size_t)n;
    // payload (16 floats/particle) lives in out[6n .. 22n) — dead until g2p overwrites
    float4* payload = (float4*)(out + 6 * (size_t)n);
    int* tab    = (int*)(out + 22 * (size_t)n);
    int* cnt    = tab;                       // GC
    int* tstart = tab + GC;                  // GC + 1
    int* cursor = tab + 2 * GC + 1;          // GC
    int* aux    = tab + 3 * GC + 1;          // 1024

    int pblocks = (n + 255) / 256;

    if (use_tiled) {
        hipMemsetAsync(cnt, 0, (size_t)GC * sizeof(int), stream);
        count_kernel<<<pblocks, 256, 0, stream>>>(x, cnt, n);
        scanA<<<GC / 256, 256, 0, stream>>>(cnt, tstart, aux);
        scanB<<<1, 256, 0, stream>>>(aux, tstart);
        scanC<<<GC / 256, 256, 0, stream>>>(tstart, aux, cursor);
        reorder_kernel<<<pblocks, 256, 0, stream>>>(x, v, C, st, cursor, payload, n);
        p2g_cell8<<<GC / 32, 256, 0, stream>>>(payload, tstart, grid);
        // grid normalize/gravity/boundary fused into p2g_cell8
    } else {
        hipMemsetAsync(grid, 0, grid_bytes, stream);
        p2g_naive<<<pblocks, 256, 0, stream>>>(x, v, C, st, grid, n);
        grid_kernel<<<GC / 256, 256, 0, stream>>>(grid);
    }

    g2p_kernel<<<pblocks, 256, 0, stream>>>(x, F, grid, out_x, out_v, out_C, out_F, n);
}

// Round 9
// 338.658 us; speedup vs baseline: 1.2838x; 1.1538x over previous
//
#include <hip/hip_runtime.h>
#include <math.h>

namespace {
constexpr int   NG    = 64;
constexpr int   GC    = NG * NG * NG;
constexpr int   BOUND = 3;
constexpr float DXf    = 1.0f / 64.0f;
constexpr float INV_DX = 64.0f;
constexpr float DTf    = 5e-4f;
constexpr double P_VOL_D = (0.5 / 64.0) * (0.5 / 64.0) * (0.5 / 64.0);
constexpr float P_MASS_F = (float)(P_VOL_D * 1000.0);
constexpr float AFFINE_SCALE = (float)(-5e-4 * P_VOL_D * 4.0 * 64.0 * 64.0);
constexpr float D_INV  = 4.0f * 64.0f * 64.0f;   // 16384
constexpr float GRAV_Y = -9.8f;

__device__ __forceinline__ void atom_add_f32(float* p, float v) {
    unsafeAtomicAdd(p, v);   // hw global_atomic_add_f32, fire-and-forget
}

__device__ __forceinline__ void weights_of(float fx0, float fx1, float fx2, float w[3][3]) {
    w[0][0] = 0.5f*(1.5f-fx0)*(1.5f-fx0); w[0][1] = 0.5f*(1.5f-fx1)*(1.5f-fx1); w[0][2] = 0.5f*(1.5f-fx2)*(1.5f-fx2);
    w[1][0] = 0.75f-(fx0-1.0f)*(fx0-1.0f); w[1][1] = 0.75f-(fx1-1.0f)*(fx1-1.0f); w[1][2] = 0.75f-(fx2-1.0f)*(fx2-1.0f);
    w[2][0] = 0.5f*(fx0-0.5f)*(fx0-0.5f); w[2][1] = 0.5f*(fx1-0.5f)*(fx1-0.5f); w[2][2] = 0.5f*(fx2-0.5f)*(fx2-0.5f);
}

// quadratic B-spline weight at signed offset u; 0 outside |u|<1.5.
// Bit-exact equal to the reference per-offset formulas for u = fx - o.
__device__ __forceinline__ float bspline_w(float u) {
    float au = fabsf(u);
    float a  = 1.5f - au;
    float w  = (au < 0.5f) ? (0.75f - u * u) : (0.5f * a * a);
    return (au < 1.5f) ? w : 0.f;
}
}

// ---------------- pass 1: histogram particles into CELLS (262144 bins) -------
__global__ __launch_bounds__(256) void count_kernel(const float* __restrict__ x,
                                                    int* __restrict__ cnt, int n)
{
    int p = blockIdx.x * 256 + threadIdx.x;
    if (p >= n) return;
    float u0 = x[3*p] * INV_DX, u1 = x[3*p+1] * INV_DX, u2 = x[3*p+2] * INV_DX;
    int b0 = (int)floorf(u0 - 0.5f), b1 = (int)floorf(u1 - 0.5f), b2 = (int)floorf(u2 - 0.5f);
    if ((unsigned)b0 >= 64u || (unsigned)b1 >= 64u || (unsigned)b2 >= 64u) return;
    atomicAdd(&cnt[((b0 << 6) + b1) * 64 + b2], 1);
}

// ---------------- pass 2a: per-256-block exclusive scan, block totals to aux --
__global__ __launch_bounds__(256) void scanA(const int* __restrict__ cnt,
                                             int* __restrict__ start,
                                             int* __restrict__ aux)
{
    __shared__ int sh[256];
    int tid = threadIdx.x;
    int i = blockIdx.x * 256 + tid;
    int v = cnt[i];
    sh[tid] = v;
    __syncthreads();
    for (int off = 1; off < 256; off <<= 1) {
        int t = (tid >= off) ? sh[tid - off] : 0;
        __syncthreads();
        sh[tid] += t;
        __syncthreads();
    }
    start[i] = sh[tid] - v;                 // block-local exclusive
    if (tid == 255) aux[blockIdx.x] = sh[255];
}

// ---------------- pass 2b: scan the 1024 block totals (single block) ---------
__global__ __launch_bounds__(256) void scanB(int* __restrict__ aux,
                                             int* __restrict__ start)
{
    __shared__ int partial[256];
    int tid = threadIdx.x;
    int local[4];
    int s = 0;
#pragma unroll
    for (int i = 0; i < 4; ++i) { local[i] = s; s += aux[tid * 4 + i]; }
    partial[tid] = s;
    __syncthreads();
    for (int off = 1; off < 256; off <<= 1) {
        int v = (tid >= off) ? partial[tid - off] : 0;
        __syncthreads();
        partial[tid] += v;
        __syncthreads();
    }
    int base = (tid > 0) ? partial[tid - 1] : 0;
#pragma unroll
    for (int i = 0; i < 4; ++i) aux[tid * 4 + i] = base + local[i];
    if (tid == 255) start[GC] = partial[255];   // grand total sentinel
}

// ---------------- pass 2c: add block offsets, emit start & cursor ------------
__global__ __launch_bounds__(256) void scanC(int* __restrict__ start,
                                             const int* __restrict__ aux,
                                             int* __restrict__ cursor)
{
    int i = blockIdx.x * 256 + threadIdx.x;
    int v = start[i] + aux[blockIdx.x];
    start[i] = v;
    cursor[i] = v;
}

// ---------------- pass 3: reorder — coalesced read, precompute, payload write
// payload record (64B): [af00,af01,af02,af10][af11,af12,af20,af21][af22,mv0,mv1,mv2][u0,u1,u2,-]
// where u = x*INV_DX is the grid-space position (base+fx combined).
__global__ __launch_bounds__(256) void reorder_kernel(const float* __restrict__ x,
                                                      const float* __restrict__ v,
                                                      const float* __restrict__ C,
                                                      const float* __restrict__ st,
                                                      int* __restrict__ cursor,
                                                      float4* __restrict__ payload, int n)
{
    int p = blockIdx.x * 256 + threadIdx.x;
    if (p >= n) return;

    float u0 = x[3*p] * INV_DX, u1 = x[3*p+1] * INV_DX, u2 = x[3*p+2] * INV_DX;
    int b0 = (int)floorf(u0 - 0.5f), b1 = (int)floorf(u1 - 0.5f), b2 = (int)floorf(u2 - 0.5f);
    if ((unsigned)b0 >= 64u || (unsigned)b1 >= 64u || (unsigned)b2 >= 64u) return;

    float aff[9];
#pragma unroll
    for (int i = 0; i < 9; ++i)
        aff[i] = st[9*p + i] * AFFINE_SCALE + P_MASS_F * C[9*p + i];
    float mv0 = P_MASS_F * v[3*p], mv1 = P_MASS_F * v[3*p+1], mv2 = P_MASS_F * v[3*p+2];

    int pos = atomicAdd(&cursor[((b0 << 6) + b1) * 64 + b2], 1);

    float4* dst = payload + 4 * (size_t)pos;
    dst[0] = make_float4(aff[0], aff[1], aff[2], aff[3]);
    dst[1] = make_float4(aff[4], aff[5], aff[6], aff[7]);
    dst[2] = make_float4(aff[8], mv0, mv1, mv2);
    dst[3] = make_float4(u0, u1, u2, 0.f);
}

// ---------------- pass 4: strip-gather P2G — 4 cells per thread --------------
// One wave (64 thr) per half-row: 8 k-strips of 4 cells x 8 segment-threads.
// Thread (strip sl, seg q) scans payload bins [g2b-2, g2b+3] of row
// (g0-q/3, g1-q%3) — ONE fetch covers all 4 strip cells (halves the
// round-8 record-fetch count, which was the TA/L1 request-rate floor).
// Per record: w01/m0..m2 once; per cell only bspline(u2)+4 FMA, branchless
// (w=0 outside support adds exact 0). Segment 8 shared by 8 lanes stride 8.
// Register-pipelined loads; 16 named accumulators (no arrays -> no scratch).
// 3-step shfl butterfly merges the 8 segment-lanes; q==0 stores 4 contiguous
// float4 cells with fused normalize+gravity+boundary. No atomics, no LDS.
__global__ __launch_bounds__(64) void p2g_strip(const float4* __restrict__ payload,
                                                const int* __restrict__ start,
                                                float* __restrict__ grid)
{
    // XCD-interleaved chunk swizzle (bijective, 8192 blocks): each XCD gets
    // chunks of 16 consecutive block-ids (= 8 consecutive (g0,g1) rows ->
    // shared payload rows in its L2), chunks interleaved for load balance.
    int w   = blockIdx.x;
    int xcd = w & 7, j = w >> 3;
    int cj  = j >> 4, oj = j & 15;
    int r   = cj * 128 + xcd * 16 + oj;      // [0, 8192)

    int row01 = r >> 1;                      // (g0,g1) row id
    int g0 = row01 >> 6, g1 = row01 & 63;
    int tid = threadIdx.x;
    int sl = tid >> 3, q = tid & 7;          // 8 strips x 8 segment-threads
    int g2b = ((r & 1) << 5) + sl * 4;       // strip base cell (4 cells)
    float fg0 = (float)g0, fg1 = (float)g1, fg2b = (float)g2b;

    float a00=0.f,a01=0.f,a02=0.f,a03=0.f;   // cell g2b+0
    float a10=0.f,a11=0.f,a12=0.f,a13=0.f;   // cell g2b+1
    float a20=0.f,a21=0.f,a22=0.f,a23=0.f;   // cell g2b+2
    float a30=0.f,a31=0.f,a32=0.f,a33=0.f;   // cell g2b+3

    int klo = (g2b >= 2) ? g2b - 2 : 0;
    int khi = (g2b + 3 <= 63) ? g2b + 3 : 63;     // inclusive

#define P2G_CELL(CC, A0, A1, A2, A3)                                         \
    {   float u2  = r3.z - (fg2b + (float)CC);                               \
        float w2  = bspline_w(u2);                                           \
        float wq  = w01 * w2;                                                \
        float dp2 = -u2 * DXf;                                               \
        A0 += wq * (m0 + r0.z * dp2);                                        \
        A1 += wq * (m1 + r1.y * dp2);                                        \
        A2 += wq * (m2 + r2.x * dp2);                                        \
        A3 += wq * P_MASS_F; }

#define P2G_SEG(SS, QOFF, STRIDE)                                            \
    {   int o0 = (SS) / 3, o1 = (SS) % 3;                                    \
        int b0 = g0 - o0, b1 = g1 - o1;                                      \
        if ((unsigned)b0 < 64u && (unsigned)b1 < 64u) {                      \
            int rowp = ((b0 << 6) + b1) << 6;                                \
            int s = start[rowp + klo] + (QOFF);                              \
            int e = start[rowp + khi + 1];                                   \
            float4 c0, c1, c2, c3;                                           \
            if (s < e) {                                                     \
                const float4* rp = payload + 4 * (size_t)s;                  \
                c0 = rp[0]; c1 = rp[1]; c2 = rp[2]; c3 = rp[3];              \
            }                                                                \
            for (int idx = s; idx < e; ) {                                   \
                float4 r0 = c0, r1 = c1, r2 = c2, r3 = c3;                   \
                idx += (STRIDE);                                             \
                if (idx < e) {                                               \
                    const float4* rp = payload + 4 * (size_t)idx;            \
                    c0 = rp[0]; c1 = rp[1]; c2 = rp[2]; c3 = rp[3];          \
                }                                                            \
                float u0  = r3.x - fg0, u1 = r3.y - fg1;                     \
                float w01 = bspline_w(u0) * bspline_w(u1);                   \
                float dp0 = -u0 * DXf, dp1 = -u1 * DXf;                      \
                float m0 = r2.y + r0.x * dp0 + r0.y * dp1;                   \
                float m1 = r2.z + r0.w * dp0 + r1.x * dp1;                   \
                float m2 = r2.w + r1.z * dp0 + r1.w * dp1;                   \
                P2G_CELL(0, a00, a01, a02, a03)                              \
                P2G_CELL(1, a10, a11, a12, a13)                              \
                P2G_CELL(2, a20, a21, a22, a23)                              \
                P2G_CELL(3, a30, a31, a32, a33)                              \
            }                                                                \
        }                                                                    \
    }

    P2G_SEG(q, 0, 1)          // own segment, dense scan
    P2G_SEG(8, q, 8)          // segment 8 shared by all 8 lanes, stride 8
#undef P2G_SEG
#undef P2G_CELL

    // butterfly reduction over the 8-lane segment group
#define RED(OFF)                                                             \
    a00 += __shfl_down(a00, OFF); a01 += __shfl_down(a01, OFF);              \
    a02 += __shfl_down(a02, OFF); a03 += __shfl_down(a03, OFF);              \
    a10 += __shfl_down(a10, OFF); a11 += __shfl_down(a11, OFF);              \
    a12 += __shfl_down(a12, OFF); a13 += __shfl_down(a13, OFF);              \
    a20 += __shfl_down(a20, OFF); a21 += __shfl_down(a21, OFF);              \
    a22 += __shfl_down(a22, OFF); a23 += __shfl_down(a23, OFF);              \
    a30 += __shfl_down(a30, OFF); a31 += __shfl_down(a31, OFF);              \
    a32 += __shfl_down(a32, OFF); a33 += __shfl_down(a33, OFF);
    RED(1) RED(2) RED(4)
#undef RED

    if (q == 0) {
#define STORE_CELL(CC, A0, A1, A2, A3)                                       \
    {   int g2 = g2b + CC;                                                   \
        float v0 = 0.f, v1 = 0.f, v2 = 0.f;                                  \
        if (A3 > 0.f) {                                                      \
            float mm = fmaxf(A3, 1e-10f);                                    \
            v0 = A0 / mm;                                                    \
            v1 = A1 / mm + DTf * GRAV_Y;                                     \
            v2 = A2 / mm;                                                    \
        }                                                                    \
        if ((g0 < BOUND && v0 < 0.f) || (g0 >= NG - BOUND && v0 > 0.f)) v0 = 0.f; \
        if ((g1 < BOUND && v1 < 0.f) || (g1 >= NG - BOUND && v1 > 0.f)) v1 = 0.f; \
        if ((g2 < BOUND && v2 < 0.f) || (g2 >= NG - BOUND && v2 > 0.f)) v2 = 0.f; \
        ((float4*)grid)[row01 * 64 + g2] = make_float4(v0, v1, v2, A3); }
        STORE_CELL(0, a00, a01, a02, a03)
        STORE_CELL(1, a10, a11, a12, a13)
        STORE_CELL(2, a20, a21, a22, a23)
        STORE_CELL(3, a30, a31, a32, a33)
#undef STORE_CELL
    }
}

// ---------------- fallback P2G: direct global atomics ----------------
__global__ __launch_bounds__(256) void p2g_naive(const float* __restrict__ x,
                                                 const float* __restrict__ v,
                                                 const float* __restrict__ C,
                                                 const float* __restrict__ st,
                                                 float* __restrict__ grid, int n)
{
    int p = blockIdx.x * 256 + threadIdx.x;
    if (p >= n) return;

    float xp0 = x[3*p], xp1 = x[3*p+1], xp2 = x[3*p+2];
    float u0 = xp0 * INV_DX, u1 = xp1 * INV_DX, u2 = xp2 * INV_DX;
    float b0f = floorf(u0 - 0.5f), b1f = floorf(u1 - 0.5f), b2f = floorf(u2 - 0.5f);
    int base0 = (int)b0f, base1 = (int)b1f, base2 = (int)b2f;
    float fx0 = u0 - b0f, fx1 = u1 - b1f, fx2 = u2 - b2f;

    float w[3][3];
    weights_of(fx0, fx1, fx2, w);

    float aff[3][3];
#pragma unroll
    for (int i = 0; i < 3; ++i)
#pragma unroll
        for (int j = 0; j < 3; ++j)
            aff[i][j] = st[9*p + 3*i + j] * AFFINE_SCALE + P_MASS_F * C[9*p + 3*i + j];

    float mv0 = P_MASS_F * v[3*p], mv1 = P_MASS_F * v[3*p+1], mv2 = P_MASS_F * v[3*p+2];

#pragma unroll
    for (int i = 0; i < 3; ++i) {
        float dp0 = ((float)i - fx0) * DXf;
#pragma unroll
        for (int j = 0; j < 3; ++j) {
            float dp1 = ((float)j - fx1) * DXf;
            float wij = w[i][0] * w[j][1];
            float m0 = mv0 + aff[0][0]*dp0 + aff[0][1]*dp1;
            float m1 = mv1 + aff[1][0]*dp0 + aff[1][1]*dp1;
            float m2 = mv2 + aff[2][0]*dp0 + aff[2][1]*dp1;
            int cellij = ((base0 + i) * NG + (base1 + j)) * NG + base2;
#pragma unroll
            for (int k = 0; k < 3; ++k) {
                float dp2 = ((float)k - fx2) * DXf;
                float wi = wij * w[k][2];
                float* cptr = grid + 4 * (cellij + k);
                atom_add_f32(cptr + 0, wi * (m0 + aff[0][2]*dp2));
                atom_add_f32(cptr + 1, wi * (m1 + aff[1][2]*dp2));
                atom_add_f32(cptr + 2, wi * (m2 + aff[2][2]*dp2));
                atom_add_f32(cptr + 3, wi * P_MASS_F);
            }
        }
    }
}

// ---------------- grid: normalize, gravity, boundary (fallback path only) ----
__global__ __launch_bounds__(256) void grid_kernel(float* __restrict__ grid)
{
    int g = blockIdx.x * 256 + threadIdx.x;
    if (g >= GC) return;
    float4 val = ((const float4*)grid)[g];
    float m = val.w;
    float v0 = 0.f, v1 = 0.f, v2 = 0.f;
    if (m > 0.f) {
        float mm = fmaxf(m, 1e-10f);
        v0 = val.x / mm;
        v1 = val.y / mm + DTf * GRAV_Y;
        v2 = val.z / mm;
    }
    int ci = g >> 12, cj = (g >> 6) & 63, ck = g & 63;
    if ((ci < BOUND && v0 < 0.f) || (ci >= NG - BOUND && v0 > 0.f)) v0 = 0.f;
    if ((cj < BOUND && v1 < 0.f) || (cj >= NG - BOUND && v1 > 0.f)) v1 = 0.f;
    if ((ck < BOUND && v2 < 0.f) || (ck >= NG - BOUND && v2 > 0.f)) v2 = 0.f;
    ((float4*)grid)[g] = make_float4(v0, v1, v2, m);
}

// ---------------- G2P: gather, advect, update C/F ----------------
__global__ __launch_bounds__(256) void g2p_kernel(const float* __restrict__ x,
                                                  const float* __restrict__ F,
                                                  const float* __restrict__ grid,
                                                  float* __restrict__ out_x,
                                                  float* __restrict__ out_v,
                                                  float* __restrict__ out_C,
                                                  float* __restrict__ out_F,
                                                  int n)
{
    int p = blockIdx.x * 256 + threadIdx.x;
    if (p >= n) return;

    float xp0 = x[3*p], xp1 = x[3*p+1], xp2 = x[3*p+2];
    float t0 = xp0 * INV_DX, t1 = xp1 * INV_DX, t2 = xp2 * INV_DX;
    float b0 = floorf(t0 - 0.5f), b1 = floorf(t1 - 0.5f), b2 = floorf(t2 - 0.5f);
    int   base0 = (int)b0, base1 = (int)b1, base2 = (int)b2;
    float fx0 = t0 - b0, fx1 = t1 - b1, fx2 = t2 - b2;

    float w[3][3];
    weights_of(fx0, fx1, fx2, w);

    float vn0 = 0.f, vn1 = 0.f, vn2 = 0.f;
    float Cn[3][3] = {};

#pragma unroll
    for (int i = 0; i < 3; ++i) {
        float dp0 = ((float)i - fx0) * DXf;
#pragma unroll
        for (int j = 0; j < 3; ++j) {
            float dp1 = ((float)j - fx1) * DXf;
            float wij = w[i][0] * w[j][1];
            int cellij = ((base0 + i) * NG + (base1 + j)) * NG + base2;
#pragma unroll
            for (int k = 0; k < 3; ++k) {
                float dp2 = ((float)k - fx2) * DXf;
                float wi = wij * w[k][2];
                float4 gv = ((const float4*)grid)[cellij + k];
                vn0 += wi * gv.x; vn1 += wi * gv.y; vn2 += wi * gv.z;
                float wx = wi * gv.x, wy = wi * gv.y, wz = wi * gv.z;
                Cn[0][0] += wx * dp0; Cn[0][1] += wx * dp1; Cn[0][2] += wx * dp2;
                Cn[1][0] += wy * dp0; Cn[1][1] += wy * dp1; Cn[1][2] += wy * dp2;
                Cn[2][0] += wz * dp0; Cn[2][1] += wz * dp1; Cn[2][2] += wz * dp2;
            }
        }
    }

#pragma unroll
    for (int i = 0; i < 3; ++i)
#pragma unroll
        for (int j = 0; j < 3; ++j)
            Cn[i][j] *= D_INV;

    out_x[3*p]   = xp0 + DTf * vn0;
    out_x[3*p+1] = xp1 + DTf * vn1;
    out_x[3*p+2] = xp2 + DTf * vn2;
    out_v[3*p]   = vn0; out_v[3*p+1] = vn1; out_v[3*p+2] = vn2;

    float Fp[3][3];
#pragma unroll
    for (int i = 0; i < 3; ++i)
#pragma unroll
        for (int j = 0; j < 3; ++j)
            Fp[i][j] = F[9*p + 3*i + j];

#pragma unroll
    for (int i = 0; i < 3; ++i) {
#pragma unroll
        for (int k = 0; k < 3; ++k) {
            float acc = Cn[i][0]*Fp[0][k] + Cn[i][1]*Fp[1][k] + Cn[i][2]*Fp[2][k];
            out_F[9*p + 3*i + k] = Fp[i][k] + DTf * acc;
            out_C[9*p + 3*i + k] = Cn[i][k];
        }
    }
}

extern "C" void kernel_launch(void* const* d_in, const int* in_sizes, int n_in,
                              void* d_out, int out_size, void* d_ws, size_t ws_size,
                              hipStream_t stream)
{
    const float* x  = (const float*)d_in[0];
    const float* v  = (const float*)d_in[1];
    const float* C  = (const float*)d_in[2];
    const float* F  = (const float*)d_in[3];
    const float* st = (const float*)d_in[4];
    int n = in_sizes[0] / 3;            // in_sizes are ELEMENT counts (floats)

    const size_t grid_bytes = (size_t)GC * 4 * sizeof(float);          // 4 MiB
    // tables live in the dead out-tail [22n, 22n+tab_ints):
    // cnt(GC) + start(GC+1) + cursor(GC) + aux(1024) = 787,457 ints
    const size_t tab_ints   = 3 * (size_t)GC + 1 + 1024;
    // out_size is an ELEMENT count (same units as in_sizes): out = 24n floats,
    // need payload[6n..22n) + tables -> 22n + tab_ints <= out_size.
    const bool   use_tiled  = ws_size >= grid_bytes &&
                              (size_t)out_size >= 22 * (size_t)n + tab_ints;

    float* grid = (float*)d_ws;

    float* out  = (float*)d_out;
    float* out_x = out;
    float* out_v = out + 3 * (size_t)n;
    float* out_C = out + 6 * (size_t)n;
    float* out_F = out + 15 * (size_t)n;
    // payload (16 floats/particle) lives in out[6n .. 22n) — dead until g2p overwrites
    float4* payload = (float4*)(out + 6 * (size_t)n);
    int* tab    = (int*)(out + 22 * (size_t)n);
    int* cnt    = tab;                       // GC
    int* tstart = tab + GC;                  // GC + 1
    int* cursor = tab + 2 * GC + 1;          // GC
    int* aux    = tab + 3 * GC + 1;          // 1024

    int pblocks = (n + 255) / 256;

    if (use_tiled) {
        hipMemsetAsync(cnt, 0, (size_t)GC * sizeof(int), stream);
        count_kernel<<<pblocks, 256, 0, stream>>>(x, cnt, n);
        scanA<<<GC / 256, 256, 0, stream>>>(cnt, tstart, aux);
        scanB<<<1, 256, 0, stream>>>(aux, tstart);
        scanC<<<GC / 256, 256, 0, stream>>>(tstart, aux, cursor);
        reorder_kernel<<<pblocks, 256, 0, stream>>>(x, v, C, st, cursor, payload, n);
        p2g_strip<<<GC / 32, 64, 0, stream>>>(payload, tstart, grid);
        // grid normalize/gravity/boundary fused into p2g_strip
    } else {
        hipMemsetAsync(grid, 0, grid_bytes, stream);
        p2g_naive<<<pblocks, 256, 0, stream>>>(x, v, C, st, grid, n);
        grid_kernel<<<GC / 256, 256, 0, stream>>>(grid);
    }

    g2p_kernel<<<pblocks, 256, 0, stream>>>(x, F, grid, out_x, out_v, out_C, out_F, n);
}

// Round 10
// 320.183 us; speedup vs baseline: 1.3579x; 1.0577x over previous
//
#include <hip/hip_runtime.h>
#include <math.h>

namespace {
constexpr int   NG    = 64;
constexpr int   GC    = NG * NG * NG;
constexpr int   BOUND = 3;
constexpr float DXf    = 1.0f / 64.0f;
constexpr float INV_DX = 64.0f;
constexpr float DTf    = 5e-4f;
constexpr double P_VOL_D = (0.5 / 64.0) * (0.5 / 64.0) * (0.5 / 64.0);
constexpr float P_MASS_F = (float)(P_VOL_D * 1000.0);
constexpr float AFFINE_SCALE = (float)(-5e-4 * P_VOL_D * 4.0 * 64.0 * 64.0);
constexpr float D_INV  = 4.0f * 64.0f * 64.0f;   // 16384
constexpr float GRAV_Y = -9.8f;

__device__ __forceinline__ void atom_add_f32(float* p, float v) {
    unsafeAtomicAdd(p, v);   // hw global_atomic_add_f32, fire-and-forget
}

__device__ __forceinline__ void weights_of(float fx0, float fx1, float fx2, float w[3][3]) {
    w[0][0] = 0.5f*(1.5f-fx0)*(1.5f-fx0); w[0][1] = 0.5f*(1.5f-fx1)*(1.5f-fx1); w[0][2] = 0.5f*(1.5f-fx2)*(1.5f-fx2);
    w[1][0] = 0.75f-(fx0-1.0f)*(fx0-1.0f); w[1][1] = 0.75f-(fx1-1.0f)*(fx1-1.0f); w[1][2] = 0.75f-(fx2-1.0f)*(fx2-1.0f);
    w[2][0] = 0.5f*(fx0-0.5f)*(fx0-0.5f); w[2][1] = 0.5f*(fx1-0.5f)*(fx1-0.5f); w[2][2] = 0.5f*(fx2-0.5f)*(fx2-0.5f);
}

// quadratic B-spline weight at signed offset u; 0 outside |u|<1.5.
// Bit-exact equal to the reference per-offset formulas for u = fx - o.
__device__ __forceinline__ float bspline_w(float u) {
    float au = fabsf(u);
    float a  = 1.5f - au;
    float w  = (au < 0.5f) ? (0.75f - u * u) : (0.5f * a * a);
    return (au < 1.5f) ? w : 0.f;
}
}

// ---------------- pass 1: histogram particles into CELLS (262144 bins) -------
__global__ __launch_bounds__(256) void count_kernel(const float* __restrict__ x,
                                                    int* __restrict__ cnt, int n)
{
    int p = blockIdx.x * 256 + threadIdx.x;
    if (p >= n) return;
    float u0 = x[3*p] * INV_DX, u1 = x[3*p+1] * INV_DX, u2 = x[3*p+2] * INV_DX;
    int b0 = (int)floorf(u0 - 0.5f), b1 = (int)floorf(u1 - 0.5f), b2 = (int)floorf(u2 - 0.5f);
    if ((unsigned)b0 >= 64u || (unsigned)b1 >= 64u || (unsigned)b2 >= 64u) return;
    atomicAdd(&cnt[((b0 << 6) + b1) * 64 + b2], 1);
}

// ---------------- pass 2a: per-256-block exclusive scan, block totals to aux --
__global__ __launch_bounds__(256) void scanA(const int* __restrict__ cnt,
                                             int* __restrict__ start,
                                             int* __restrict__ aux)
{
    __shared__ int sh[256];
    int tid = threadIdx.x;
    int i = blockIdx.x * 256 + tid;
    int v = cnt[i];
    sh[tid] = v;
    __syncthreads();
    for (int off = 1; off < 256; off <<= 1) {
        int t = (tid >= off) ? sh[tid - off] : 0;
        __syncthreads();
        sh[tid] += t;
        __syncthreads();
    }
    start[i] = sh[tid] - v;                 // block-local exclusive
    if (tid == 255) aux[blockIdx.x] = sh[255];
}

// ---------------- pass 2b: add block offsets (each block re-scans aux in LDS),
//                  emit start & cursor, block 0 writes the grand-total sentinel.
__global__ __launch_bounds__(256) void scanC(int* __restrict__ start,
                                             const int* __restrict__ aux,
                                             int* __restrict__ cursor)
{
    __shared__ int partial[256];
    __shared__ int sa[1024];
    int tid = threadIdx.x;
    int local[4];
    int s = 0;
#pragma unroll
    for (int k = 0; k < 4; ++k) { local[k] = s; s += aux[tid * 4 + k]; }
    partial[tid] = s;
    __syncthreads();
    for (int off = 1; off < 256; off <<= 1) {
        int v = (tid >= off) ? partial[tid - off] : 0;
        __syncthreads();
        partial[tid] += v;
        __syncthreads();
    }
    int base = (tid > 0) ? partial[tid - 1] : 0;
#pragma unroll
    for (int k = 0; k < 4; ++k) sa[tid * 4 + k] = base + local[k];
    __syncthreads();
    int off0 = sa[blockIdx.x];              // exclusive prefix of aux at this block
    int i = blockIdx.x * 256 + tid;
    int v = start[i] + off0;
    start[i] = v;
    cursor[i] = v;
    if (blockIdx.x == 0 && tid == 0) start[GC] = sa[1023] + aux[1023];
}

// ---------------- pass 3: reorder — coalesced read, precompute, SoA payload
// SoA payload, 4 arrays of float4[n]:
//  pay0=[af00,af01,af02,af10]  pay1=[af11,af12,af20,af21]
//  pay2=[af22,mv0,mv1,mv2]     pay3=[u0,u1,u2,-]   (u = x*INV_DX)
__global__ __launch_bounds__(256) void reorder_kernel(const float* __restrict__ x,
                                                      const float* __restrict__ v,
                                                      const float* __restrict__ C,
                                                      const float* __restrict__ st,
                                                      int* __restrict__ cursor,
                                                      float4* __restrict__ pay0,
                                                      float4* __restrict__ pay1,
                                                      float4* __restrict__ pay2,
                                                      float4* __restrict__ pay3, int n)
{
    int p = blockIdx.x * 256 + threadIdx.x;
    if (p >= n) return;

    float u0 = x[3*p] * INV_DX, u1 = x[3*p+1] * INV_DX, u2 = x[3*p+2] * INV_DX;
    int b0 = (int)floorf(u0 - 0.5f), b1 = (int)floorf(u1 - 0.5f), b2 = (int)floorf(u2 - 0.5f);
    if ((unsigned)b0 >= 64u || (unsigned)b1 >= 64u || (unsigned)b2 >= 64u) return;

    float aff[9];
#pragma unroll
    for (int i = 0; i < 9; ++i)
        aff[i] = st[9*p + i] * AFFINE_SCALE + P_MASS_F * C[9*p + i];
    float mv0 = P_MASS_F * v[3*p], mv1 = P_MASS_F * v[3*p+1], mv2 = P_MASS_F * v[3*p+2];

    int pos = atomicAdd(&cursor[((b0 << 6) + b1) * 64 + b2], 1);

    pay0[pos] = make_float4(aff[0], aff[1], aff[2], aff[3]);
    pay1[pos] = make_float4(aff[4], aff[5], aff[6], aff[7]);
    pay2[pos] = make_float4(aff[8], mv0, mv1, mv2);
    pay3[pos] = make_float4(u0, u1, u2, 0.f);
}

// ---------------- pass 4: strip-gather P2G, cooperative SoA loads ------------
// One wave (64 thr) per half-row: 8 k-strips of 4 cells x 8 lanes. All 8 lanes
// of a strip walk EACH of the 9 (o0,o1) row-segments together at stride 8
// (lane q takes record s+q): with the SoA payload, one load instruction covers
// 8 consecutive 16B elements per strip-group = 2 cache lines instead of 8 -->
// ~4x fewer TA line-requests than round-9's lane-per-segment AoS walk (the
// measured request-rate floor). Per-record VALU is unchanged: each record is
// processed once per strip (w01/m0..m2 once, then 4 branchless cell updates).
// Register-pipelined; 16 named accumulators; 3-step shfl butterfly merges the
// 8 lanes; q==0 stores 4 contiguous float4 cells with fused normalize +
// gravity + boundary. No atomics, no LDS, exact 27-cell support.
__global__ __launch_bounds__(64) void p2g_strip(const float4* __restrict__ pay0,
                                                const float4* __restrict__ pay1,
                                                const float4* __restrict__ pay2,
                                                const float4* __restrict__ pay3,
                                                const int* __restrict__ start,
                                                float* __restrict__ grid)
{
    // XCD-interleaved chunk swizzle (bijective, 8192 blocks): each XCD gets
    // chunks of 16 consecutive block-ids (= 8 consecutive (g0,g1) rows ->
    // shared payload rows in its L2), chunks interleaved for load balance.
    int w   = blockIdx.x;
    int xcd = w & 7, j = w >> 3;
    int cj  = j >> 4, oj = j & 15;
    int r   = cj * 128 + xcd * 16 + oj;      // [0, 8192)

    int row01 = r >> 1;                      // (g0,g1) row id
    int g0 = row01 >> 6, g1 = row01 & 63;
    int tid = threadIdx.x;
    int sl = tid >> 3, q = tid & 7;          // 8 strips x 8 cooperative lanes
    int g2b = ((r & 1) << 5) + sl * 4;       // strip base cell (4 cells)
    float fg0 = (float)g0, fg1 = (float)g1, fg2b = (float)g2b;

    float a00=0.f,a01=0.f,a02=0.f,a03=0.f;   // cell g2b+0
    float a10=0.f,a11=0.f,a12=0.f,a13=0.f;   // cell g2b+1
    float a20=0.f,a21=0.f,a22=0.f,a23=0.f;   // cell g2b+2
    float a30=0.f,a31=0.f,a32=0.f,a33=0.f;   // cell g2b+3

    int klo = (g2b >= 2) ? g2b - 2 : 0;
    int khi = (g2b + 3 <= 63) ? g2b + 3 : 63;     // inclusive

#define P2G_CELL(CC, A0, A1, A2, A3)                                         \
    {   float u2  = r3.z - (fg2b + (float)CC);                               \
        float w2  = bspline_w(u2);                                           \
        float wq  = w01 * w2;                                                \
        float dp2 = -u2 * DXf;                                               \
        A0 += wq * (m0 + r0.z * dp2);                                        \
        A1 += wq * (m1 + r1.y * dp2);                                        \
        A2 += wq * (m2 + r2.x * dp2);                                        \
        A3 += wq * P_MASS_F; }

#pragma unroll
    for (int o0 = 0; o0 < 3; ++o0) {
        int b0 = g0 - o0;
        if ((unsigned)b0 >= 64u) continue;
#pragma unroll
        for (int o1 = 0; o1 < 3; ++o1) {
            int b1 = g1 - o1;
            if ((unsigned)b1 >= 64u) continue;
            int rowp = ((b0 << 6) + b1) << 6;
            int s = start[rowp + klo] + q;       // lane q takes s+q, s+q+8, ...
            int e = start[rowp + khi + 1];
            float4 c0, c1, c2, c3;
            if (s < e) { c0 = pay0[s]; c1 = pay1[s]; c2 = pay2[s]; c3 = pay3[s]; }
            for (int idx = s; idx < e; ) {
                float4 r0 = c0, r1 = c1, r2 = c2, r3 = c3;
                idx += 8;
                if (idx < e) { c0 = pay0[idx]; c1 = pay1[idx]; c2 = pay2[idx]; c3 = pay3[idx]; }
                float u0  = r3.x - fg0, u1 = r3.y - fg1;
                float w01 = bspline_w(u0) * bspline_w(u1);
                float dp0 = -u0 * DXf, dp1 = -u1 * DXf;
                float m0 = r2.y + r0.x * dp0 + r0.y * dp1;
                float m1 = r2.z + r0.w * dp0 + r1.x * dp1;
                float m2 = r2.w + r1.z * dp0 + r1.w * dp1;
                P2G_CELL(0, a00, a01, a02, a03)
                P2G_CELL(1, a10, a11, a12, a13)
                P2G_CELL(2, a20, a21, a22, a23)
                P2G_CELL(3, a30, a31, a32, a33)
            }
        }
    }
#undef P2G_CELL

    // butterfly reduction over the 8-lane strip group
#define RED(OFF)                                                             \
    a00 += __shfl_down(a00, OFF); a01 += __shfl_down(a01, OFF);              \
    a02 += __shfl_down(a02, OFF); a03 += __shfl_down(a03, OFF);              \
    a10 += __shfl_down(a10, OFF); a11 += __shfl_down(a11, OFF);              \
    a12 += __shfl_down(a12, OFF); a13 += __shfl_down(a13, OFF);              \
    a20 += __shfl_down(a20, OFF); a21 += __shfl_down(a21, OFF);              \
    a22 += __shfl_down(a22, OFF); a23 += __shfl_down(a23, OFF);              \
    a30 += __shfl_down(a30, OFF); a31 += __shfl_down(a31, OFF);              \
    a32 += __shfl_down(a32, OFF); a33 += __shfl_down(a33, OFF);
    RED(1) RED(2) RED(4)
#undef RED

    if (q == 0) {
#define STORE_CELL(CC, A0, A1, A2, A3)                                       \
    {   int g2 = g2b + CC;                                                   \
        float v0 = 0.f, v1 = 0.f, v2 = 0.f;                                  \
        if (A3 > 0.f) {                                                      \
            float mm = fmaxf(A3, 1e-10f);                                    \
            v0 = A0 / mm;                                                    \
            v1 = A1 / mm + DTf * GRAV_Y;                                     \
            v2 = A2 / mm;                                                    \
        }                                                                    \
        if ((g0 < BOUND && v0 < 0.f) || (g0 >= NG - BOUND && v0 > 0.f)) v0 = 0.f; \
        if ((g1 < BOUND && v1 < 0.f) || (g1 >= NG - BOUND && v1 > 0.f)) v1 = 0.f; \
        if ((g2 < BOUND && v2 < 0.f) || (g2 >= NG - BOUND && v2 > 0.f)) v2 = 0.f; \
        ((float4*)grid)[row01 * 64 + g2] = make_float4(v0, v1, v2, A3); }
        STORE_CELL(0, a00, a01, a02, a03)
        STORE_CELL(1, a10, a11, a12, a13)
        STORE_CELL(2, a20, a21, a22, a23)
        STORE_CELL(3, a30, a31, a32, a33)
#undef STORE_CELL
    }
}

// ---------------- fallback P2G: direct global atomics ----------------
__global__ __launch_bounds__(256) void p2g_naive(const float* __restrict__ x,
                                                 const float* __restrict__ v,
                                                 const float* __restrict__ C,
                                                 const float* __restrict__ st,
                                                 float* __restrict__ grid, int n)
{
    int p = blockIdx.x * 256 + threadIdx.x;
    if (p >= n) return;

    float xp0 = x[3*p], xp1 = x[3*p+1], xp2 = x[3*p+2];
    float u0 = xp0 * INV_DX, u1 = xp1 * INV_DX, u2 = xp2 * INV_DX;
    float b0f = floorf(u0 - 0.5f), b1f = floorf(u1 - 0.5f), b2f = floorf(u2 - 0.5f);
    int base0 = (int)b0f, base1 = (int)b1f, base2 = (int)b2f;
    float fx0 = u0 - b0f, fx1 = u1 - b1f, fx2 = u2 - b2f;

    float w[3][3];
    weights_of(fx0, fx1, fx2, w);

    float aff[3][3];
#pragma unroll
    for (int i = 0; i < 3; ++i)
#pragma unroll
        for (int j = 0; j < 3; ++j)
            aff[i][j] = st[9*p + 3*i + j] * AFFINE_SCALE + P_MASS_F * C[9*p + 3*i + j];

    float mv0 = P_MASS_F * v[3*p], mv1 = P_MASS_F * v[3*p+1], mv2 = P_MASS_F * v[3*p+2];

#pragma unroll
    for (int i = 0; i < 3; ++i) {
        float dp0 = ((float)i - fx0) * DXf;
#pragma unroll
        for (int j = 0; j < 3; ++j) {
            float dp1 = ((float)j - fx1) * DXf;
            float wij = w[i][0] * w[j][1];
            float m0 = mv0 + aff[0][0]*dp0 + aff[0][1]*dp1;
            float m1 = mv1 + aff[1][0]*dp0 + aff[1][1]*dp1;
            float m2 = mv2 + aff[2][0]*dp0 + aff[2][1]*dp1;
            int cellij = ((base0 + i) * NG + (base1 + j)) * NG + base2;
#pragma unroll
            for (int k = 0; k < 3; ++k) {
                float dp2 = ((float)k - fx2) * DXf;
                float wi = wij * w[k][2];
                float* cptr = grid + 4 * (cellij + k);
                atom_add_f32(cptr + 0, wi * (m0 + aff[0][2]*dp2));
                atom_add_f32(cptr + 1, wi * (m1 + aff[1][2]*dp2));
                atom_add_f32(cptr + 2, wi * (m2 + aff[2][2]*dp2));
                atom_add_f32(cptr + 3, wi * P_MASS_F);
            }
        }
    }
}

// ---------------- grid: normalize, gravity, boundary (fallback path only) ----
__global__ __launch_bounds__(256) void grid_kernel(float* __restrict__ grid)
{
    int g = blockIdx.x * 256 + threadIdx.x;
    if (g >= GC) return;
    float4 val = ((const float4*)grid)[g];
    float m = val.w;
    float v0 = 0.f, v1 = 0.f, v2 = 0.f;
    if (m > 0.f) {
        float mm = fmaxf(m, 1e-10f);
        v0 = val.x / mm;
        v1 = val.y / mm + DTf * GRAV_Y;
        v2 = val.z / mm;
    }
    int ci = g >> 12, cj = (g >> 6) & 63, ck = g & 63;
    if ((ci < BOUND && v0 < 0.f) || (ci >= NG - BOUND && v0 > 0.f)) v0 = 0.f;
    if ((cj < BOUND && v1 < 0.f) || (cj >= NG - BOUND && v1 > 0.f)) v1 = 0.f;
    if ((ck < BOUND && v2 < 0.f) || (ck >= NG - BOUND && v2 > 0.f)) v2 = 0.f;
    ((float4*)grid)[g] = make_float4(v0, v1, v2, m);
}

// ---------------- G2P: gather, advect, update C/F ----------------
__global__ __launch_bounds__(256) void g2p_kernel(const float* __restrict__ x,
                                                  const float* __restrict__ F,
                                                  const float* __restrict__ grid,
                                                  float* __restrict__ out_x,
                                                  float* __restrict__ out_v,
                                                  float* __restrict__ out_C,
                                                  float* __restrict__ out_F,
                                                  int n)
{
    int p = blockIdx.x * 256 + threadIdx.x;
    if (p >= n) return;

    float xp0 = x[3*p], xp1 = x[3*p+1], xp2 = x[3*p+2];
    float t0 = xp0 * INV_DX, t1 = xp1 * INV_DX, t2 = xp2 * INV_DX;
    float b0 = floorf(t0 - 0.5f), b1 = floorf(t1 - 0.5f), b2 = floorf(t2 - 0.5f);
    int   base0 = (int)b0, base1 = (int)b1, base2 = (int)b2;
    float fx0 = t0 - b0, fx1 = t1 - b1, fx2 = t2 - b2;

    float w[3][3];
    weights_of(fx0, fx1, fx2, w);

    float vn0 = 0.f, vn1 = 0.f, vn2 = 0.f;
    float Cn[3][3] = {};

#pragma unroll
    for (int i = 0; i < 3; ++i) {
        float dp0 = ((float)i - fx0) * DXf;
#pragma unroll
        for (int j = 0; j < 3; ++j) {
            float dp1 = ((float)j - fx1) * DXf;
            float wij = w[i][0] * w[j][1];
            int cellij = ((base0 + i) * NG + (base1 + j)) * NG + base2;
#pragma unroll
            for (int k = 0; k < 3; ++k) {
                float dp2 = ((float)k - fx2) * DXf;
                float wi = wij * w[k][2];
                float4 gv = ((const float4*)grid)[cellij + k];
                vn0 += wi * gv.x; vn1 += wi * gv.y; vn2 += wi * gv.z;
                float wx = wi * gv.x, wy = wi * gv.y, wz = wi * gv.z;
                Cn[0][0] += wx * dp0; Cn[0][1] += wx * dp1; Cn[0][2] += wx * dp2;
                Cn[1][0] += wy * dp0; Cn[1][1] += wy * dp1; Cn[1][2] += wy * dp2;
                Cn[2][0] += wz * dp0; Cn[2][1] += wz * dp1; Cn[2][2] += wz * dp2;
            }
        }
    }

#pragma unroll
    for (int i = 0; i < 3; ++i)
#pragma unroll
        for (int j = 0; j < 3; ++j)
            Cn[i][j] *= D_INV;

    out_x[3*p]   = xp0 + DTf * vn0;
    out_x[3*p+1] = xp1 + DTf * vn1;
    out_x[3*p+2] = xp2 + DTf * vn2;
    out_v[3*p]   = vn0; out_v[3*p+1] = vn1; out_v[3*p+2] = vn2;

    float Fp[3][3];
#pragma unroll
    for (int i = 0; i < 3; ++i)
#pragma unroll
        for (int j = 0; j < 3; ++j)
            Fp[i][j] = F[9*p + 3*i + j];

#pragma unroll
    for (int i = 0; i < 3; ++i) {
#pragma unroll
        for (int k = 0; k < 3; ++k) {
            float acc = Cn[i][0]*Fp[0][k] + Cn[i][1]*Fp[1][k] + Cn[i][2]*Fp[2][k];
            out_F[9*p + 3*i + k] = Fp[i][k] + DTf * acc;
            out_C[9*p + 3*i + k] = Cn[i][k];
        }
    }
}

extern "C" void kernel_launch(void* const* d_in, const int* in_sizes, int n_in,
                              void* d_out, int out_size, void* d_ws, size_t ws_size,
                              hipStream_t stream)
{
    const float* x  = (const float*)d_in[0];
    const float* v  = (const float*)d_in[1];
    const float* C  = (const float*)d_in[2];
    const float* F  = (const float*)d_in[3];
    const float* st = (const float*)d_in[4];
    int n = in_sizes[0] / 3;            // in_sizes are ELEMENT counts (floats)

    const size_t grid_bytes = (size_t)GC * 4 * sizeof(float);          // 4 MiB
    // tables live in the dead out-tail [22n, 22n+tab_ints):
    // cnt(GC) + start(GC+1) + cursor(GC) + aux(1024) = 787,457 ints
    const size_t tab_ints   = 3 * (size_t)GC + 1 + 1024;
    // out_size is an ELEMENT count (same units as in_sizes): out = 24n floats,
    // need payload[6n..22n) + tables -> 22n + tab_ints <= out_size.
    const bool   use_tiled  = ws_size >= grid_bytes &&
                              (size_t)out_size >= 22 * (size_t)n + tab_ints;

    float* grid = (float*)d_ws;

    float* out  = (float*)d_out;
    float* out_x = out;
    float* out_v = out + 3 * (size_t)n;
    float* out_C = out + 6 * (size_t)n;
    float* out_F = out + 15 * (size_t)n;
    // SoA payload (4 arrays of float4[n] = 16n floats) lives in out[6n .. 22n)
    // — dead until g2p overwrites
    float4* pay0 = (float4*)(out + 6 * (size_t)n);
    float4* pay1 = pay0 + (size_t)n;
    float4* pay2 = pay0 + 2 * (size_t)n;
    float4* pay3 = pay0 + 3 * (size_t)n;
    int* tab    = (int*)(out + 22 * (size_t)n);
    int* cnt    = tab;                       // GC
    int* tstart = tab + GC;                  // GC + 1
    int* cursor = tab + 2 * GC + 1;          // GC
    int* aux    = tab + 3 * GC + 1;          // 1024

    int pblocks = (n + 255) / 256;

    if (use_tiled) {
        hipMemsetAsync(cnt, 0, (size_t)GC * sizeof(int), stream);
        count_kernel<<<pblocks, 256, 0, stream>>>(x, cnt, n);
        scanA<<<GC / 256, 256, 0, stream>>>(cnt, tstart, aux);
        scanC<<<GC / 256, 256, 0, stream>>>(tstart, aux, cursor);
        reorder_kernel<<<pblocks, 256, 0, stream>>>(x, v, C, st, cursor,
                                                    pay0, pay1, pay2, pay3, n);
        p2g_strip<<<GC / 32, 64, 0, stream>>>(pay0, pay1, pay2, pay3, tstart, grid);
        // grid normalize/gravity/boundary fused into p2g_strip
    } else {
        hipMemsetAsync(grid, 0, grid_bytes, stream);
        p2g_naive<<<pblocks, 256, 0, stream>>>(x, v, C, st, grid, n);
        grid_kernel<<<GC / 256, 256, 0, stream>>>(grid);
    }

    g2p_kernel<<<pblocks, 256, 0, stream>>>(x, F, grid, out_x, out_v, out_C, out_F, n);
}